// Round 7
// baseline (141.345 us; speedup 1.0000x reference)
//
#include <hip/hip_runtime.h>
#include <cmath>

#define NB 8
#define DIM 4096
#define NHQ 32
#define NHKV 8
#define NDH 128
#define MAXSEQ 4096
#define STARTPOS 4095
#define QKV_COLS 6144   // 4096 q + 1024 k + 1024 v
#define RCHUNK 64       // rows per split-K chunk
#define NRC 64          // 4096 / 64
#define SCALE 0.08838834764831845f  // 1/sqrt(128)

#define DOT4(k, qq) ((k).x*(qq).x + (k).y*(qq).y + (k).z*(qq).z + (k).w*(qq).w)

// async global->LDS, 16B per lane, dest = wave-uniform base + lane*16
__device__ __forceinline__ void gl_lds16(const float* g, float* l) {
  __builtin_amdgcn_global_load_lds(
      (const __attribute__((address_space(1))) unsigned int*)g,
      (__attribute__((address_space(3))) unsigned int*)l, 16, 0, 0);
}

// ---------------------------------------------------------------------------
// Kernel 1: QKV projection partials.  grid = 12 col-tiles * 64 row-chunks.
__global__ __launch_bounds__(256) void qkv_partial_k(
    const float* __restrict__ x, const float* __restrict__ wq,
    const float* __restrict__ wk, const float* __restrict__ wv,
    float* __restrict__ part) {
  int bid = blockIdx.x;
  int ct = bid % 12, rc = bid / 12;
  int tid = threadIdx.x;
  const float* W; int ldw; int colbase;
  int gcolbase = ct * 512;
  if (ct < 8)       { W = wq; ldw = NHQ * NDH;  colbase = gcolbase; }
  else if (ct < 10) { W = wk; ldw = NHKV * NDH; colbase = gcolbase - 4096; }
  else              { W = wv; ldw = NHKV * NDH; colbase = gcolbase - 5120; }

  __shared__ __align__(16) float xs[RCHUNK][8];
  int rbase = rc * RCHUNK;
  for (int i = tid; i < RCHUNK * 8; i += 256) {
    int b = i >> 6, r = i & 63;
    xs[r][b] = x[b * DIM + rbase + r];
  }
  __syncthreads();

  int col = colbase + tid * 2;
  const float* wp = W + (size_t)rbase * ldw + col;
  float2 acc[8];
#pragma unroll
  for (int b = 0; b < 8; b++) { acc[b].x = 0.f; acc[b].y = 0.f; }

#pragma unroll 8
  for (int r = 0; r < RCHUNK; r++) {
    float2 w2 = *(const float2*)wp; wp += ldw;
    float4 xa = *(const float4*)&xs[r][0];
    float4 xb = *(const float4*)&xs[r][4];
    acc[0].x += xa.x * w2.x; acc[0].y += xa.x * w2.y;
    acc[1].x += xa.y * w2.x; acc[1].y += xa.y * w2.y;
    acc[2].x += xa.z * w2.x; acc[2].y += xa.z * w2.y;
    acc[3].x += xa.w * w2.x; acc[3].y += xa.w * w2.y;
    acc[4].x += xb.x * w2.x; acc[4].y += xb.x * w2.y;
    acc[5].x += xb.y * w2.x; acc[5].y += xb.y * w2.y;
    acc[6].x += xb.z * w2.x; acc[6].y += xb.z * w2.y;
    acc[7].x += xb.w * w2.x; acc[7].y += xb.w * w2.y;
  }
  int gcol = gcolbase + tid * 2;
#pragma unroll
  for (int b = 0; b < 8; b++)
    *(float2*)&part[((size_t)rc * 8 + b) * QKV_COLS + gcol] = acc[b];
}

// ---------------------------------------------------------------------------
// Kernel 2: reduce partials + bias + RoPE (pos = STARTPOS).  49152 threads.
__global__ __launch_bounds__(256) void qkv_reduce_rope_k(
    const float* __restrict__ part, const float* __restrict__ bq,
    const float* __restrict__ bk, const float* __restrict__ bv,
    float* __restrict__ qws, float* __restrict__ kws, float* __restrict__ vws) {
  int idx = blockIdx.x * 256 + threadIdx.x;
  int b = idx / QKV_COLS, col = idx % QKV_COLS;
  float s = 0.f;
#pragma unroll 8
  for (int rcc = 0; rcc < NRC; rcc++)
    s += part[((size_t)rcc * 8 + b) * QKV_COLS + col];
  float bias = (col < 4096) ? bq[col] : (col < 5120 ? bk[col - 4096] : bv[col - 5120]);
  s += bias;
  float outv = s;
  if (col < 5120) {  // q or k -> RoPE
    int dim = col & 127;
    int i2 = dim & ~1;
    float theta = powf(10000.f, -(float)i2 * (1.f / 128.f));
    float ang = (float)STARTPOS * theta;
    float c = cosf(ang), sn = sinf(ang);
    float other = __shfl_xor(s, 1);
    if ((col & 1) == 0) outv = s * c - other * sn;   // xr*cos - xi*sin
    else                outv = other * sn + s * c;   // xr*sin + xi*cos
  }
  if (col < 4096)       qws[b * 4096 + col] = outv;
  else if (col < 5120)  kws[b * 1024 + (col - 4096)] = outv;
  else                  vws[b * 1024 + (col - 5120)] = outv;
}

// ---------------------------------------------------------------------------
// Kernel 3 (NEW): fused flash attention with global_load_lds staging.
// grid = 64 (b,hkv) groups * 4 chunks of 1024 t = 256 blocks = 1 block/CU.
// 256 thr = 4 waves; wave = q-head.  Tiles of 64 t; K+V double-buffered in
// LDS (131 KB).  2-phase: sync -> stage(next) -> compute(cur).  K staged with
// XOR pre-swizzled SOURCE addresses so lane-per-row ds_read_b128 is at the
// LDS structural minimum; V staged linear (row reads are contiguous).
__global__ __launch_bounds__(256) void flash_k(
    const float* __restrict__ qws, const float* __restrict__ kws,
    const float* __restrict__ vws, const float* __restrict__ ck,
    const float* __restrict__ cv, float* __restrict__ pm,
    float* __restrict__ pl, float* __restrict__ pacc) {
  int bid = blockIdx.x;
  int group = bid >> 2, chunk = bid & 3;
  int b = group >> 3, hkv = group & 7;
  int tid = threadIdx.x;
  int w = tid >> 6, lane = tid & 63;

  __shared__ __align__(16) float kbuf[2][64][128];
  __shared__ __align__(16) float vbuf[2][64][128];
  __shared__ __align__(16) float qs[4][128];
  __shared__ float pbuf[4][64];

  // one-time: q (4 heads x 128) -> LDS
  if (tid < 128) {
    int h = tid >> 5, d4 = (tid & 31) * 4;
    *(float4*)&qs[h][d4] =
        *(const float4*)(qws + ((size_t)b * NHQ + hkv * 4 + h) * NDH + d4);
  }

  const int t0c = chunk * 1024;
  const int srow8 = tid >> 5;   // row-within-round (0..7), includes wave bits
  const int slot  = tid & 31;   // 16B slot within a 512B row
  const float* kwsrow = kws + ((size_t)b * NHKV + hkv) * NDH;
  const float* vwsrow = vws + ((size_t)b * NHKV + hkv) * NDH;

  // Stage one 64t tile (K swizzled-source, V linear): 8 rounds x (K+V),
  // 16 gload_lds per wave, no dest VGPRs -> deep queue guaranteed.
#define STAGE(bufi_, tile_) do {                                              \
    int tb_ = t0c + (tile_) * 64;                                             \
    float* kdst_ = &kbuf[bufi_][0][0] + w * 256;                              \
    float* vdst_ = &vbuf[bufi_][0][0] + w * 256;                              \
    _Pragma("unroll")                                                         \
    for (int i_ = 0; i_ < 8; i_++) {                                          \
      int row_ = i_ * 8 + srow8;                                              \
      int t_ = tb_ + row_;                                                    \
      int ks_ = slot ^ (row_ & 7);                                            \
      const float* kg_ = (t_ == STARTPOS) ? (kwsrow + ks_ * 4)                \
          : (ck + ((size_t)(b * MAXSEQ + t_) * NHKV + hkv) * NDH + ks_ * 4);  \
      gl_lds16(kg_, kdst_ + i_ * 1024);                                       \
      const float* vg_ = (t_ == STARTPOS) ? (vwsrow + slot * 4)               \
          : (cv + ((size_t)(b * MAXSEQ + t_) * NHKV + hkv) * NDH + slot * 4); \
      gl_lds16(vg_, vdst_ + i_ * 1024);                                       \
    }                                                                         \
  } while (0)

  float2 acc = {0.f, 0.f};
  float m_run = -1e30f, l_run = 0.f;

  STAGE(0, 0);

  for (int tile = 0; tile < 16; ++tile) {
    int bufi = tile & 1;
    __syncthreads();                 // drains vmcnt -> buf[bufi] staged
    if (tile < 15) STAGE(bufi ^ 1, tile + 1);

    // ---- scores: lane = t-row, wave = head ----
    float s = 0.f;
#pragma unroll
    for (int j = 0; j < 32; j++) {
      float4 kf = *(const float4*)&kbuf[bufi][lane][4 * (j ^ (lane & 7))];
      float4 qf = *(const float4*)&qs[w][j * 4];
      s += DOT4(kf, qf);
    }
    s *= SCALE;

    // ---- online softmax (wave-parallel) ----
    float mt = s;
#pragma unroll
    for (int off = 32; off; off >>= 1) mt = fmaxf(mt, __shfl_xor(mt, off));
    float mn = fmaxf(m_run, mt);
    float al = expf(m_run - mn);
    float p = expf(s - mn);
    float lt = p;
#pragma unroll
    for (int off = 32; off; off >>= 1) lt += __shfl_xor(lt, off);
    l_run = l_run * al + lt;
    m_run = mn;
    pbuf[w][lane] = p;               // same-wave producer/consumer
    acc.x *= al; acc.y *= al;

    // ---- PV: lane = d-pair, iterate 64 t ----
#pragma unroll 8
    for (int t = 0; t < 64; t++) {
      float pp = pbuf[w][t];
      float2 v2 = *(const float2*)&vbuf[bufi][t][lane * 2];
      acc.x += pp * v2.x;
      acc.y += pp * v2.y;
    }
  }
#undef STAGE

  *(float2*)&pacc[((size_t)bid * 4 + w) * NDH + lane * 2] = acc;
  if (lane == 0) {
    pm[bid * 4 + w] = m_run;
    pl[bid * 4 + w] = l_run;
  }
}

// ---------------------------------------------------------------------------
// Kernel 4: combine 4 chunk partials per (b,hq).  grid 256, block 128.
__global__ __launch_bounds__(128) void attn_combine_k(
    const float* __restrict__ pm, const float* __restrict__ pl,
    const float* __restrict__ pacc, float* __restrict__ aout) {
  int bid = blockIdx.x;
  int b = bid >> 5, hq = bid & 31;
  int group = b * 8 + (hq >> 2), r = hq & 3;
  int d = threadIdx.x;
  float mv[4];
  float M = -1e30f;
#pragma unroll
  for (int c = 0; c < 4; c++) {
    mv[c] = pm[(group * 4 + c) * 4 + r];
    M = fmaxf(M, mv[c]);
  }
  float L = 0.f;
  float wgt[4];
#pragma unroll
  for (int c = 0; c < 4; c++) {
    wgt[c] = expf(mv[c] - M);
    L += wgt[c] * pl[(group * 4 + c) * 4 + r];
  }
  float o = 0.f;
#pragma unroll
  for (int c = 0; c < 4; c++)
    o += wgt[c] * pacc[((size_t)(group * 4 + c) * 4 + r) * NDH + d];
  aout[(size_t)b * 4096 + hq * NDH + d] = o / L;
}

// ---------------------------------------------------------------------------
// Kernel 5: output projection partials. grid = 8 col-tiles * 64 row-chunks.
__global__ __launch_bounds__(256) void out_partial_k(
    const float* __restrict__ ain, const float* __restrict__ wo,
    float* __restrict__ part) {
  int bid = blockIdx.x;
  int ct = bid & 7, rc = bid >> 3;
  int tid = threadIdx.x;
  __shared__ __align__(16) float xs[RCHUNK][8];
  int rbase = rc * RCHUNK;
  for (int i = tid; i < RCHUNK * 8; i += 256) {
    int b = i >> 6, r = i & 63;
    xs[r][b] = ain[(size_t)b * 4096 + rbase + r];
  }
  __syncthreads();

  int col = ct * 512 + tid * 2;
  const float* wp = wo + (size_t)rbase * 4096 + col;
  float2 acc[8];
#pragma unroll
  for (int b = 0; b < 8; b++) { acc[b].x = 0.f; acc[b].y = 0.f; }
#pragma unroll 8
  for (int r = 0; r < RCHUNK; r++) {
    float2 w2 = *(const float2*)wp; wp += 4096;
    float4 xa = *(const float4*)&xs[r][0];
    float4 xb = *(const float4*)&xs[r][4];
    acc[0].x += xa.x * w2.x; acc[0].y += xa.x * w2.y;
    acc[1].x += xa.y * w2.x; acc[1].y += xa.y * w2.y;
    acc[2].x += xa.z * w2.x; acc[2].y += xa.z * w2.y;
    acc[3].x += xa.w * w2.x; acc[3].y += xa.w * w2.y;
    acc[4].x += xb.x * w2.x; acc[4].y += xb.x * w2.y;
    acc[5].x += xb.y * w2.x; acc[5].y += xb.y * w2.y;
    acc[6].x += xb.z * w2.x; acc[6].y += xb.z * w2.y;
    acc[7].x += xb.w * w2.x; acc[7].y += xb.w * w2.y;
  }
#pragma unroll
  for (int b = 0; b < 8; b++)
    *(float2*)&part[((size_t)rc * 8 + b) * 4096 + col] = acc[b];
}

// ---------------------------------------------------------------------------
// Kernel 6: reduce wo partials + bias -> d_out.  32768 threads.
__global__ __launch_bounds__(256) void out_reduce_k(
    const float* __restrict__ part, const float* __restrict__ bo,
    float* __restrict__ out) {
  int idx = blockIdx.x * 256 + threadIdx.x;
  int b = idx >> 12, col = idx & 4095;
  float s = bo[col];
#pragma unroll 8
  for (int rcc = 0; rcc < NRC; rcc++)
    s += part[((size_t)rcc * 8 + b) * 4096 + col];
  out[idx] = s;
  (void)b;
}

// ---------------------------------------------------------------------------
extern "C" void kernel_launch(void* const* d_in, const int* in_sizes, int n_in,
                              void* d_out, int out_size, void* d_ws, size_t ws_size,
                              hipStream_t stream) {
  const float* x       = (const float*)d_in[0];
  const float* wq      = (const float*)d_in[1];
  const float* bq      = (const float*)d_in[2];
  const float* wk      = (const float*)d_in[3];
  const float* bk      = (const float*)d_in[4];
  const float* wv      = (const float*)d_in[5];
  const float* bv      = (const float*)d_in[6];
  const float* wo      = (const float*)d_in[7];
  const float* bo      = (const float*)d_in[8];
  const float* cache_k = (const float*)d_in[9];
  const float* cache_v = (const float*)d_in[10];
  float* out = (float*)d_out;

  float* ws = (float*)d_ws;
  // region0 [0, 3,145,728): qkv_part, then wo_part (qkv dead by then)
  float* qkv_part = ws;
  float* wo_part  = ws;
  float* qws  = ws + 3145728;                 // 32768
  float* kws  = ws + 3178496;                 // 8192
  float* vws  = ws + 3186688;                 // 8192
  float* pm   = ws + 3194880;                 // 1024  (256 blocks * 4 heads)
  float* pl   = ws + 3195904;                 // 1024
  float* pacc = ws + 3196928;                 // 131072 (256 * 4 * 128)
  float* aout = ws + 3328000;                 // 32768 -> end 3,360,768 (13.4 MB)

  qkv_partial_k<<<768, 256, 0, stream>>>(x, wq, wk, wv, qkv_part);
  qkv_reduce_rope_k<<<192, 256, 0, stream>>>(qkv_part, bq, bk, bv, qws, kws, vws);
  flash_k<<<256, 256, 0, stream>>>(qws, kws, vws, cache_k, cache_v, pm, pl, pacc);
  attn_combine_k<<<256, 128, 0, stream>>>(pm, pl, pacc, aout);
  out_partial_k<<<512, 256, 0, stream>>>(aout, wo, wo_part);
  out_reduce_k<<<128, 256, 0, stream>>>(wo_part, bo, out);
}

// Round 8
// 125.056 us; speedup vs baseline: 1.1303x; 1.1303x over previous
//
#include <hip/hip_runtime.h>
#include <cmath>

#define NB 8
#define DIM 4096
#define NHQ 32
#define NHKV 8
#define NDH 128
#define MAXSEQ 4096
#define STARTPOS 4095
#define QKV_COLS 6144   // 4096 q + 1024 k + 1024 v
#define RCHUNK 64       // rows per split-K chunk
#define NRC 64          // 4096 / 64
#define SCALE 0.08838834764831845f  // 1/sqrt(128)
#define NCHUNK 64       // attn chunks per batch
#define CPOS 64         // t positions per attn chunk

#define DOT4(k, qq) ((k).x*(qq).x + (k).y*(qq).y + (k).z*(qq).z + (k).w*(qq).w)

// ---------------------------------------------------------------------------
// Kernel 1: QKV projection partials.  grid = 12 col-tiles * 64 row-chunks.
__global__ __launch_bounds__(256) void qkv_partial_k(
    const float* __restrict__ x, const float* __restrict__ wq,
    const float* __restrict__ wk, const float* __restrict__ wv,
    float* __restrict__ part) {
  int bid = blockIdx.x;
  int ct = bid % 12, rc = bid / 12;
  int tid = threadIdx.x;
  const float* W; int ldw; int colbase;
  int gcolbase = ct * 512;
  if (ct < 8)       { W = wq; ldw = NHQ * NDH;  colbase = gcolbase; }
  else if (ct < 10) { W = wk; ldw = NHKV * NDH; colbase = gcolbase - 4096; }
  else              { W = wv; ldw = NHKV * NDH; colbase = gcolbase - 5120; }

  __shared__ __align__(16) float xs[RCHUNK][8];
  int rbase = rc * RCHUNK;
  for (int i = tid; i < RCHUNK * 8; i += 256) {
    int b = i >> 6, r = i & 63;
    xs[r][b] = x[b * DIM + rbase + r];
  }
  __syncthreads();

  int col = colbase + tid * 2;
  const float* wp = W + (size_t)rbase * ldw + col;
  float2 acc[8];
#pragma unroll
  for (int b = 0; b < 8; b++) { acc[b].x = 0.f; acc[b].y = 0.f; }

#pragma unroll 8
  for (int r = 0; r < RCHUNK; r++) {
    float2 w2 = *(const float2*)wp; wp += ldw;
    float4 xa = *(const float4*)&xs[r][0];
    float4 xb = *(const float4*)&xs[r][4];
    acc[0].x += xa.x * w2.x; acc[0].y += xa.x * w2.y;
    acc[1].x += xa.y * w2.x; acc[1].y += xa.y * w2.y;
    acc[2].x += xa.z * w2.x; acc[2].y += xa.z * w2.y;
    acc[3].x += xa.w * w2.x; acc[3].y += xa.w * w2.y;
    acc[4].x += xb.x * w2.x; acc[4].y += xb.x * w2.y;
    acc[5].x += xb.y * w2.x; acc[5].y += xb.y * w2.y;
    acc[6].x += xb.z * w2.x; acc[6].y += xb.z * w2.y;
    acc[7].x += xb.w * w2.x; acc[7].y += xb.w * w2.y;
  }
  int gcol = gcolbase + tid * 2;
#pragma unroll
  for (int b = 0; b < 8; b++)
    *(float2*)&part[((size_t)rc * 8 + b) * QKV_COLS + gcol] = acc[b];
}

// ---------------------------------------------------------------------------
// Kernel 2: reduce partials + bias + RoPE (pos = STARTPOS).  49152 threads.
__global__ __launch_bounds__(256) void qkv_reduce_rope_k(
    const float* __restrict__ part, const float* __restrict__ bq,
    const float* __restrict__ bk, const float* __restrict__ bv,
    float* __restrict__ qws, float* __restrict__ kws, float* __restrict__ vws) {
  int idx = blockIdx.x * 256 + threadIdx.x;
  int b = idx / QKV_COLS, col = idx % QKV_COLS;
  float s = 0.f;
#pragma unroll 8
  for (int rcc = 0; rcc < NRC; rcc++)
    s += part[((size_t)rcc * 8 + b) * QKV_COLS + col];
  float bias = (col < 4096) ? bq[col] : (col < 5120 ? bk[col - 4096] : bv[col - 5120]);
  s += bias;
  float outv = s;
  if (col < 5120) {  // q or k -> RoPE
    int dim = col & 127;
    int i2 = dim & ~1;
    float theta = powf(10000.f, -(float)i2 * (1.f / 128.f));
    float ang = (float)STARTPOS * theta;
    float c = cosf(ang), sn = sinf(ang);
    float other = __shfl_xor(s, 1);
    if ((col & 1) == 0) outv = s * c - other * sn;   // xr*cos - xi*sin
    else                outv = other * sn + s * c;   // xr*sin + xi*cos
  }
  if (col < 4096)       qws[b * 4096 + col] = outv;
  else if (col < 5120)  kws[b * 1024 + (col - 4096)] = outv;
  else                  vws[b * 1024 + (col - 5120)] = outv;
}

// ---------------------------------------------------------------------------
// Kernel 3 (NEW): one projection-shaped attention kernel.
// grid = 8 b * 64 chunks of 64 t = 512 blocks (2/CU).  256 thr = 4 waves.
// half-wave = hkv (w*2 + lane/32), lane%32 = 16B slice of d.
// Phase A: stream CONTIGUOUS 256KB K slab -> all-32-head scores via 11-op
//          butterfly; scores in 8KB LDS.
// Phase B: per-head (m,l) over the chunk; normalize P in place.
// Phase C: stream CONTIGUOUS 256KB V slab -> register accumulators; each
//          (hkv,head,slice) owned by one lane; no cross-wave reduction.
__global__ __launch_bounds__(256, 2) void attn_chunk_k(
    const float* __restrict__ qws, const float* __restrict__ kws,
    const float* __restrict__ vws, const float* __restrict__ ck,
    const float* __restrict__ cv, float* __restrict__ pm,
    float* __restrict__ pl, float* __restrict__ pacc) {
  int bid = blockIdx.x;
  int chunk = bid & 63, b = bid >> 6;
  int tid = threadIdx.x;
  int w = tid >> 6, lane = tid & 63;
  int half = lane >> 5, s32 = lane & 31;
  int hkv = w * 2 + half;
  int t0 = chunk * CPOS;

  __shared__ float sbuf[NHKV][4][65];   // [hkv][head][t] scores -> P
  __shared__ float marr[NHQ];

  // q fragments for this lane's hkv / slice (4 heads)
  const float* qb = qws + ((size_t)b * NHQ + hkv * 4) * NDH + s32 * 4;
  float4 qf0 = *(const float4*)(qb + 0 * NDH);
  float4 qf1 = *(const float4*)(qb + 1 * NDH);
  float4 qf2 = *(const float4*)(qb + 2 * NDH);
  float4 qf3 = *(const float4*)(qb + 3 * NDH);

  const float* kbase = ck + ((size_t)(b * MAXSEQ + t0) * NHKV + hkv) * NDH + s32 * 4;
  const float* vbase = cv + ((size_t)(b * MAXSEQ + t0) * NHKV + hkv) * NDH + s32 * 4;
  const float* kwsrow = kws + ((size_t)b * NHKV + hkv) * NDH + s32 * 4;
  const float* vwsrow = vws + ((size_t)b * NHKV + hkv) * NDH + s32 * 4;

  // ---- Phase A: scores over 64 t, 8 rows batched in flight ----
  for (int ii = 0; ii < CPOS; ii += 8) {
    float4 kf[8];
#pragma unroll
    for (int u = 0; u < 8; u++) {
      int t = t0 + ii + u;
      const float* kr = (t == STARTPOS) ? kwsrow : (kbase + (size_t)(ii + u) * 1024);
      kf[u] = *(const float4*)kr;
    }
#pragma unroll
    for (int u = 0; u < 8; u++) {
      float p0 = DOT4(kf[u], qf0);
      float p1 = DOT4(kf[u], qf1);
      float p2 = DOT4(kf[u], qf2);
      float p3 = DOT4(kf[u], qf3);
      // quad reduce (d-slices within quad)
      p0 += __shfl_xor(p0, 1); p0 += __shfl_xor(p0, 2);
      p1 += __shfl_xor(p1, 1); p1 += __shfl_xor(p1, 2);
      p2 += __shfl_xor(p2, 1); p2 += __shfl_xor(p2, 2);
      p3 += __shfl_xor(p3, 1); p3 += __shfl_xor(p3, 2);
      int hsel = s32 & 3;
      float v = (hsel == 0) ? p0 : (hsel == 1) ? p1 : (hsel == 2) ? p2 : p3;
      // reduce over the 8 quads (masks 4,8,16 preserve s32&3 and half)
      v += __shfl_xor(v, 4); v += __shfl_xor(v, 8); v += __shfl_xor(v, 16);
      v *= SCALE;
      if (s32 < 4) sbuf[hkv][s32][ii + u] = v;
    }
  }
  __syncthreads();

  // ---- Phase B: per-head m,l; normalize P in place ----
  {
    int hq = tid >> 3, sub = tid & 7;
    int hk = hq >> 2, hh = hq & 3;
    float m = -1e30f;
#pragma unroll
    for (int k = 0; k < 8; k++) m = fmaxf(m, sbuf[hk][hh][sub + k * 8]);
    m = fmaxf(m, __shfl_xor(m, 1));
    m = fmaxf(m, __shfl_xor(m, 2));
    m = fmaxf(m, __shfl_xor(m, 4));
    float l = 0.f;
#pragma unroll
    for (int k = 0; k < 8; k++) l += expf(sbuf[hk][hh][sub + k * 8] - m);
    l += __shfl_xor(l, 1);
    l += __shfl_xor(l, 2);
    l += __shfl_xor(l, 4);
    if (sub == 0) {
      pm[(size_t)bid * NHQ + hq] = m;
      pl[(size_t)bid * NHQ + hq] = l;
      marr[hq] = m;
    }
  }
  __syncthreads();
  {
    int hq = tid >> 3, sub = tid & 7;
    int hk = hq >> 2, hh = hq & 3;
    float m = marr[hq];
#pragma unroll
    for (int k = 0; k < 8; k++) {
      int t = sub + k * 8;
      sbuf[hk][hh][t] = expf(sbuf[hk][hh][t] - m);
    }
  }
  __syncthreads();

  // ---- Phase C: PV stream, register accumulators ----
  float4 acc0 = {0.f, 0.f, 0.f, 0.f};
  float4 acc1 = {0.f, 0.f, 0.f, 0.f};
  float4 acc2 = {0.f, 0.f, 0.f, 0.f};
  float4 acc3 = {0.f, 0.f, 0.f, 0.f};
  for (int ii = 0; ii < CPOS; ii += 8) {
    float4 vf[8];
#pragma unroll
    for (int u = 0; u < 8; u++) {
      int t = t0 + ii + u;
      const float* vr = (t == STARTPOS) ? vwsrow : (vbase + (size_t)(ii + u) * 1024);
      vf[u] = *(const float4*)vr;
    }
#pragma unroll
    for (int u = 0; u < 8; u++) {
      int tl = ii + u;
      float pp0 = sbuf[hkv][0][tl];   // broadcast within half-wave
      float pp1 = sbuf[hkv][1][tl];
      float pp2 = sbuf[hkv][2][tl];
      float pp3 = sbuf[hkv][3][tl];
      acc0.x += pp0 * vf[u].x; acc0.y += pp0 * vf[u].y;
      acc0.z += pp0 * vf[u].z; acc0.w += pp0 * vf[u].w;
      acc1.x += pp1 * vf[u].x; acc1.y += pp1 * vf[u].y;
      acc1.z += pp1 * vf[u].z; acc1.w += pp1 * vf[u].w;
      acc2.x += pp2 * vf[u].x; acc2.y += pp2 * vf[u].y;
      acc2.z += pp2 * vf[u].z; acc2.w += pp2 * vf[u].w;
      acc3.x += pp3 * vf[u].x; acc3.y += pp3 * vf[u].y;
      acc3.z += pp3 * vf[u].z; acc3.w += pp3 * vf[u].w;
    }
  }

  float* pb = pacc + ((size_t)bid * NHQ + hkv * 4) * NDH + s32 * 4;
  *(float4*)(pb + 0 * NDH) = acc0;
  *(float4*)(pb + 1 * NDH) = acc1;
  *(float4*)(pb + 2 * NDH) = acc2;
  *(float4*)(pb + 3 * NDH) = acc3;
}

// ---------------------------------------------------------------------------
// Kernel 4: combine 64 chunk partials per (b,hq).  grid 256, block 128.
__global__ __launch_bounds__(128) void attn_combine_k(
    const float* __restrict__ pm, const float* __restrict__ pl,
    const float* __restrict__ pacc, float* __restrict__ aout) {
  int bid = blockIdx.x;
  int b = bid >> 5, hq = bid & 31;
  int d = threadIdx.x;
  float M = -1e30f;
  for (int c = 0; c < NCHUNK; c++)
    M = fmaxf(M, pm[((size_t)(b * NCHUNK + c)) * NHQ + hq]);
  float L = 0.f, o = 0.f;
  for (int c = 0; c < NCHUNK; c++) {
    size_t idx = (size_t)(b * NCHUNK + c) * NHQ + hq;
    float wgt = expf(pm[idx] - M);
    L += wgt * pl[idx];
    o += wgt * pacc[idx * NDH + d];
  }
  aout[(size_t)b * 4096 + hq * NDH + d] = o / L;
}

// ---------------------------------------------------------------------------
// Kernel 5: output projection partials. grid = 8 col-tiles * 64 row-chunks.
__global__ __launch_bounds__(256) void out_partial_k(
    const float* __restrict__ ain, const float* __restrict__ wo,
    float* __restrict__ part) {
  int bid = blockIdx.x;
  int ct = bid & 7, rc = bid >> 3;
  int tid = threadIdx.x;
  __shared__ __align__(16) float xs[RCHUNK][8];
  int rbase = rc * RCHUNK;
  for (int i = tid; i < RCHUNK * 8; i += 256) {
    int b = i >> 6, r = i & 63;
    xs[r][b] = ain[(size_t)b * 4096 + rbase + r];
  }
  __syncthreads();

  int col = ct * 512 + tid * 2;
  const float* wp = wo + (size_t)rbase * 4096 + col;
  float2 acc[8];
#pragma unroll
  for (int b = 0; b < 8; b++) { acc[b].x = 0.f; acc[b].y = 0.f; }
#pragma unroll 8
  for (int r = 0; r < RCHUNK; r++) {
    float2 w2 = *(const float2*)wp; wp += 4096;
    float4 xa = *(const float4*)&xs[r][0];
    float4 xb = *(const float4*)&xs[r][4];
    acc[0].x += xa.x * w2.x; acc[0].y += xa.x * w2.y;
    acc[1].x += xa.y * w2.x; acc[1].y += xa.y * w2.y;
    acc[2].x += xa.z * w2.x; acc[2].y += xa.z * w2.y;
    acc[3].x += xa.w * w2.x; acc[3].y += xa.w * w2.y;
    acc[4].x += xb.x * w2.x; acc[4].y += xb.x * w2.y;
    acc[5].x += xb.y * w2.x; acc[5].y += xb.y * w2.y;
    acc[6].x += xb.z * w2.x; acc[6].y += xb.z * w2.y;
    acc[7].x += xb.w * w2.x; acc[7].y += xb.w * w2.y;
  }
#pragma unroll
  for (int b = 0; b < 8; b++)
    *(float2*)&part[((size_t)rc * 8 + b) * 4096 + col] = acc[b];
}

// ---------------------------------------------------------------------------
// Kernel 6: reduce wo partials + bias -> d_out.  32768 threads.
__global__ __launch_bounds__(256) void out_reduce_k(
    const float* __restrict__ part, const float* __restrict__ bo,
    float* __restrict__ out) {
  int idx = blockIdx.x * 256 + threadIdx.x;
  int b = idx >> 12, col = idx & 4095;
  float s = bo[col];
#pragma unroll 8
  for (int rcc = 0; rcc < NRC; rcc++)
    s += part[((size_t)rcc * 8 + b) * 4096 + col];
  out[idx] = s;
  (void)b;
}

// ---------------------------------------------------------------------------
extern "C" void kernel_launch(void* const* d_in, const int* in_sizes, int n_in,
                              void* d_out, int out_size, void* d_ws, size_t ws_size,
                              hipStream_t stream) {
  const float* x       = (const float*)d_in[0];
  const float* wq      = (const float*)d_in[1];
  const float* bq      = (const float*)d_in[2];
  const float* wk      = (const float*)d_in[3];
  const float* bk      = (const float*)d_in[4];
  const float* wv      = (const float*)d_in[5];
  const float* bv      = (const float*)d_in[6];
  const float* wo      = (const float*)d_in[7];
  const float* bo      = (const float*)d_in[8];
  const float* cache_k = (const float*)d_in[9];
  const float* cache_v = (const float*)d_in[10];
  float* out = (float*)d_out;

  float* ws = (float*)d_ws;
  // region0 [0, 3,145,728): qkv_part(k1 w, k2 r) -> pacc(k3 w, k4 r, 2.1M)
  //                         -> wo_part(k5 w, k6 r, 2.1M).  Serial, safe.
  float* qkv_part = ws;
  float* pacc     = ws;
  float* wo_part  = ws;
  float* qws  = ws + 3145728;                 // 32768
  float* kws  = ws + 3178496;                 // 8192
  float* vws  = ws + 3186688;                 // 8192
  float* pm   = ws + 3194880;                 // 16384 (512 blk * 32 hq)
  float* pl   = ws + 3211264;                 // 16384
  float* aout = ws + 3227648;                 // 32768 -> end 3,260,416 (13.0 MB)

  qkv_partial_k<<<768, 256, 0, stream>>>(x, wq, wk, wv, qkv_part);
  qkv_reduce_rope_k<<<192, 256, 0, stream>>>(qkv_part, bq, bk, bv, qws, kws, vws);
  attn_chunk_k<<<512, 256, 0, stream>>>(qws, kws, vws, cache_k, cache_v, pm, pl, pacc);
  attn_combine_k<<<256, 128, 0, stream>>>(pm, pl, pacc, aout);
  out_partial_k<<<512, 256, 0, stream>>>(aout, wo, wo_part);
  out_reduce_k<<<128, 256, 0, stream>>>(wo_part, bo, out);
}